// Round 12
// baseline (21531.746 us; speedup 1.0000x reference)
//
#include <hip/hip_runtime.h>
#include <math.h>

#define Bsz  128
#define Lseq 256
#define Hdim 512
#define G4   2048
#define NWG  256
#define NT   512
#define RB   32      // batch rows per wg
#define LHP  516     // padded LDS row stride (floats), 16B-aligned rows
#define OUTHALF (Bsz * Lseq * 2)   // 65536: planar split re | im

#define LH_ELEMS   (RB * LHP)                 // 16512
#define ZRED_ELEMS (2 * 2 * RB * 33)          // 4224: [kh][layer][row][col(33 pad)]
#define MLP_ELEMS  80
#define LDS_FLOATS (2 * LH_ELEMS + ZRED_ELEMS + MLP_ELEMS)  // 37328
#define LDS_BYTES  (LDS_FLOATS * 4)           // 149,312 B < 160 KiB -> 1 wg/CU

#define ZI(khh, ly, row, col) (((((khh)*2+(ly))*RB + (row))*33) + (col))

struct PArgs {
  const float *x, *Wx0, *Wh0, *b0, *Wx1, *Wh1, *b1;   // original layouts [K][4H]
  const float *Wr1, *br1, *Wr2, *br2, *Wi1, *bi1, *Wi2, *bi2;
  float *H0, *H1;                             // double-buffered [2][128][512]
  int   *cnt;                                 // 8 barrier counters (monotonic)
  float *out;                                 // f32 PLANAR: [re (B,L,2)][im (B,L,2)]
};

__device__ __forceinline__ float sigf(float z) {
  return 1.f / (1.f + expf(-z));
}

__global__ void __launch_bounds__(NT, 1) lstm_persist(PArgs A) {
  const int w    = blockIdx.x;
  const int tid  = threadIdx.x;
  // XCD-aware mapping (blockIdx -> XCD round-robin %8): XCD x hosts cs in
  // [8x,8x+8) -> 64 contiguous h-cols -> 1.5 MB weight slice per XCD L2.
  const int cs   = (w & 7) * 8 + ((w >> 3) & 7);  // 0..63
  const int bg   = w >> 6;                         // 0..3
  const int r0   = bg * RB;
  const int c0   = cs * 8;
  // GEMM mapping: thread = (k-half kh, col-quad q, row rr)
  const int q    = (tid >> 5) & 7;      // 0..7
  const int rr   = tid & 31;            // 0..31
  const int kh   = tid >> 8;            // 0..1
  const int kbase = kh << 8;            // 0 or 256
  const int gq   = (q >> 1) * Hdim + c0 + (q & 1) * 4;
  // cell mapping (tid < 256): thread = (row rr2, h-col hcc)
  const int rr2  = (tid >> 3) & 31;
  const int hcc  = tid & 7;
  // MLP mapping (tid < 256)
  const int wv   = (tid >> 6) & 3;
  const int lane = tid & 63;

  extern __shared__ float lds[];
  float* lh0  = lds;                    // h0[p-1], rows r0..r0+31
  float* lh1  = lds + LH_ELEMS;         // h1[p-2]
  float* zred = lds + 2 * LH_ELEMS;     // [2][2][32][33]
  float* mlpb = zred + ZRED_ELEMS;      // [4 waves][20]

  // per-thread cell constants (tid < 256 only)
  float b0g[4], b1g[4], wx0a[4], wx0b[4];
  if (tid < 256) {
#pragma unroll
    for (int g = 0; g < 4; ++g) {
      int gc = g * Hdim + c0 + hcc;
      b0g[g]  = A.b0[gc];
      b1g[g]  = A.b1[gc];
      wx0a[g] = A.Wx0[gc];        // one-hot row 0 (x = -1)
      wx0b[g] = A.Wx0[G4 + gc];   // one-hot row 1 (x = +1)
    }
  }
  float c0s = 0.f, c1s = 0.f;   // cell states in registers (tid < 256)

  const float4* Wx1q = (const float4*)(A.Wx1 + gq);
  const float4* Wh1q = (const float4*)(A.Wh1 + gq);
  const float4* Wh0q = (const float4*)(A.Wh0 + gq);

  for (int p = 0; p <= Lseq + 1; ++p) {
    // ---------- stage h0[p-1], h1[p-2]: 32 sc1 loads -> regs -> LDS ----------
    const unsigned long long* h0src8 =
      (const unsigned long long*)(A.H0 + (size_t)((p + 1) & 1) * (Bsz * Hdim) + (size_t)r0 * Hdim);
    const unsigned long long* h1src8 =
      (const unsigned long long*)(A.H1 + (size_t)(p & 1) * (Bsz * Hdim) + (size_t)r0 * Hdim);
    unsigned long long v0[16], v1[16];
#pragma unroll
    for (int it = 0; it < 16; ++it) {
      int e = it * NT + tid;                  // 0..8191
      v0[it] = __hip_atomic_load(&h0src8[(e >> 8) * 256 + (e & 255)],
                                 __ATOMIC_RELAXED, __HIP_MEMORY_SCOPE_AGENT);
    }
#pragma unroll
    for (int it = 0; it < 16; ++it) {
      int e = it * NT + tid;
      v1[it] = __hip_atomic_load(&h1src8[(e >> 8) * 256 + (e & 255)],
                                 __ATOMIC_RELAXED, __HIP_MEMORY_SCOPE_AGENT);
    }
#pragma unroll
    for (int it = 0; it < 16; ++it) {
      int e = it * NT + tid;
      int row = e >> 8, c2 = e & 255;
      *(unsigned long long*)&lh0[row * LHP + c2 * 2] = v0[it];
      *(unsigned long long*)&lh1[row * LHP + c2 * 2] = v1[it];
    }
    __syncthreads();                          // sync A

    const bool doL1  = (p >= 1 && p <= Lseq);
    const bool doL0  = (p < Lseq);
    const bool doMLP = (p >= 2 && cs < 32 && tid < 256);

    // issue x load early; consumed after sync B (latency hides under GEMM)
    float xv = 0.f;
    if (tid < 256 && p < Lseq) xv = A.x[(r0 + rr2) * Lseq + p];

    // ---------- fused GEMM over this thread's k-half ----------
    // z1 = relu(h0[p-1])@Wx1 + h1[p-2]@Wh1 ;  z0 = h0[p-1]@Wh0
    {
      float4 az1 = {0.f, 0.f, 0.f, 0.f};
      float4 az0 = {0.f, 0.f, 0.f, 0.f};
#pragma unroll 2
      for (int kk4 = 0; kk4 < 256; kk4 += 4) {
        const int k = kbase + kk4;
        float4 a0 = *(const float4*)&lh0[rr * LHP + k];
        float4 a1 = *(const float4*)&lh1[rr * LHP + k];
        float a0v[4] = {a0.x, a0.y, a0.z, a0.w};
        float arv[4] = {fmaxf(a0.x, 0.f), fmaxf(a0.y, 0.f), fmaxf(a0.z, 0.f), fmaxf(a0.w, 0.f)};
        float a1v[4] = {a1.x, a1.y, a1.z, a1.w};
#pragma unroll
        for (int kk = 0; kk < 4; ++kk) {
          float4 wx = Wx1q[(k + kk) * (G4 / 4)];
          float4 wh = Wh1q[(k + kk) * (G4 / 4)];
          float4 w0 = Wh0q[(k + kk) * (G4 / 4)];
          az1.x += arv[kk] * wx.x + a1v[kk] * wh.x;
          az1.y += arv[kk] * wx.y + a1v[kk] * wh.y;
          az1.z += arv[kk] * wx.z + a1v[kk] * wh.z;
          az1.w += arv[kk] * wx.w + a1v[kk] * wh.w;
          az0.x += a0v[kk] * w0.x;
          az0.y += a0v[kk] * w0.y;
          az0.z += a0v[kk] * w0.z;
          az0.w += a0v[kk] * w0.w;
        }
      }
      const int cq = q * 4;
      zred[ZI(kh, 1, rr, cq + 0)] = az1.x;
      zred[ZI(kh, 1, rr, cq + 1)] = az1.y;
      zred[ZI(kh, 1, rr, cq + 2)] = az1.z;
      zred[ZI(kh, 1, rr, cq + 3)] = az1.w;
      zred[ZI(kh, 0, rr, cq + 0)] = az0.x;
      zred[ZI(kh, 0, rr, cq + 1)] = az0.y;
      zred[ZI(kh, 0, rr, cq + 2)] = az0.z;
      zred[ZI(kh, 0, rr, cq + 3)] = az0.w;
    }

    // ---------- MLP partials (waves 0-3; reads only lh1) ----------
    if (doMLP) {
      float pr[10], pi[10];
#pragma unroll
      for (int j = 0; j < 10; ++j) { pr[j] = 0.f; pi[j] = 0.f; }
#pragma unroll
      for (int i2 = 0; i2 < 2; ++i2) {
        int k = (wv << 7) + (i2 << 6) + lane;
        float hv = fmaxf(lh1[cs * LHP + k], 0.f);
#pragma unroll
        for (int j = 0; j < 10; ++j) {
          pr[j] += hv * A.Wr1[k * 10 + j];
          pi[j] += hv * A.Wi1[k * 10 + j];
        }
      }
#pragma unroll
      for (int j = 0; j < 10; ++j)
#pragma unroll
        for (int off = 32; off >= 1; off >>= 1) {
          pr[j] += __shfl_xor(pr[j], off);
          pi[j] += __shfl_xor(pi[j], off);
        }
      if (lane == 0) {
#pragma unroll
        for (int j = 0; j < 10; ++j) { mlpb[wv * 20 + j] = pr[j]; mlpb[wv * 20 + 10 + j] = pi[j]; }
      }
    }
    __syncthreads();                          // sync B

    // ---------- cell updates (tid < 256) ----------
    if (tid < 256) {
      if (doL1) {
        float z[4];
#pragma unroll
        for (int g = 0; g < 4; ++g)
          z[g] = zred[ZI(0, 1, rr2, g * 8 + hcc)] + zred[ZI(1, 1, rr2, g * 8 + hcc)] + b1g[g];
        float ig = sigf(z[0]), fg = sigf(z[1]), gg = tanhf(z[2]), og = sigf(z[3]);
        c1s = fg * c1s + ig * gg;
        float hv = og * tanhf(c1s);
        float* H1w = A.H1 + (size_t)((p + 1) & 1) * (Bsz * Hdim);
        __hip_atomic_store(&H1w[(r0 + rr2) * Hdim + c0 + hcc], hv,
                           __ATOMIC_RELAXED, __HIP_MEMORY_SCOPE_AGENT);
      }
      if (doL0) {
        float z[4];
#pragma unroll
        for (int g = 0; g < 4; ++g)
          z[g] = zred[ZI(0, 0, rr2, g * 8 + hcc)] + zred[ZI(1, 0, rr2, g * 8 + hcc)]
               + b0g[g] + (xv > 0.f ? wx0b[g] : wx0a[g]);
        float ig = sigf(z[0]), fg = sigf(z[1]), gg = tanhf(z[2]), og = sigf(z[3]);
        c0s = fg * c0s + ig * gg;
        float hv = og * tanhf(c0s);
        float* H0w = A.H0 + (size_t)(p & 1) * (Bsz * Hdim);
        __hip_atomic_store(&H0w[(r0 + rr2) * Hdim + c0 + hcc], hv,
                           __ATOMIC_RELAXED, __HIP_MEMORY_SCOPE_AGENT);
      }
    }

    // ---------- MLP epilogue + output (f32 PLANAR re|im) ----------
    if (doMLP && tid == 0) {
      const int t = p - 2, b = r0 + cs;
      float rsum[2] = {A.br2[0], A.br2[1]};
      float isum[2] = {A.bi2[0], A.bi2[1]};
#pragma unroll
      for (int j = 0; j < 10; ++j) {
        float ar = mlpb[j] + mlpb[20 + j] + mlpb[40 + j] + mlpb[60 + j] + A.br1[j];
        ar = fmaxf(ar, 0.f);
        rsum[0] += ar * A.Wr2[j * 2];
        rsum[1] += ar * A.Wr2[j * 2 + 1];
        float ai = mlpb[10 + j] + mlpb[30 + j] + mlpb[50 + j] + mlpb[70 + j] + A.bi1[j];
        ai = fmaxf(ai, 0.f);
        isum[0] += ai * A.Wi2[j * 2];
        isum[1] += ai * A.Wi2[j * 2 + 1];
      }
#pragma unroll
      for (int m = 0; m < 2; ++m) {
        float im = 3.14159265358979323846f * (isum[m] / (1.f + fabsf(isum[m])));
        float sv, cv;
        sincosf(im, &sv, &cv);
        const int c = (b * Lseq + t) * 2 + m;
        A.out[c]           = rsum[m] * cv;   // real
        A.out[OUTHALF + c] = rsum[m] * sv;   // imag
      }
    }

    // ---------- grid barrier: 8 monotonic counters, 8 pollers per wg ----------
    __syncthreads();                          // all wg work (incl. h stores) done
    if (tid == 0) {
      __hip_atomic_fetch_add(&A.cnt[w & 7], 1, __ATOMIC_RELEASE, __HIP_MEMORY_SCOPE_AGENT);
    }
    if (tid < 8) {
      const int target = (p + 1) * (NWG / 8);
      while (__hip_atomic_load(&A.cnt[tid], __ATOMIC_ACQUIRE, __HIP_MEMORY_SCOPE_AGENT) < target) {
        __builtin_amdgcn_s_sleep(8);
      }
    }
    __syncthreads();
  }
}

extern "C" void kernel_launch(void* const* d_in, const int* in_sizes, int n_in,
                              void* d_out, int out_size, void* d_ws, size_t ws_size,
                              hipStream_t stream) {
  // Input pointers in setup_inputs() dict order; defend against an
  // alphabetically-sorted harness order via the in_sizes signature.
  const float* P[15];
  for (int i = 0; i < 15; ++i) P[i] = (const float*)d_in[i];
  if (in_sizes[0] != Bsz * Lseq) {
    static const int m_[15] = {14, 6, 0, 8, 7, 1, 9, 4, 12, 5, 13, 2, 10, 3, 11};
    for (int i = 0; i < 15; ++i) P[i] = (const float*)d_in[m_[i]];
  }

  PArgs a;
  a.x   = P[0];
  a.Wx0 = P[1];
  a.Wh0 = P[2];
  a.b0  = P[3];
  a.Wx1 = P[4];
  a.Wh1 = P[5];
  a.b1  = P[6];
  a.Wr1 = P[7];
  a.br1 = P[8];
  a.Wr2 = P[9];
  a.br2 = P[10];
  a.Wi1 = P[11];
  a.bi1 = P[12];
  a.Wi2 = P[13];
  a.bi2 = P[14];

  // workspace: H0 (2 parities) + H1 (2 parities) + counters
  float* ws = (float*)d_ws;
  a.H0 = ws;
  a.H1 = ws + 2 * Bsz * Hdim;
  a.cnt = (int*)(ws + 4 * Bsz * Hdim);
  a.out = (float*)d_out;

  // zero H state (both parities) + counters every call (replay-safe)
  hipMemsetAsync(ws, 0, (size_t)(4 * Bsz * Hdim) * sizeof(float) + NWG * sizeof(int), stream);

  hipFuncSetAttribute((const void*)lstm_persist,
                      hipFuncAttributeMaxDynamicSharedMemorySize, LDS_BYTES);
  // plain launch: 256 wgs, 1 wg/CU (forced by 149 KB LDS) on 256 CUs
  lstm_persist<<<dim3(NWG), dim3(NT), LDS_BYTES, stream>>>(a);
}

// Round 14
// 8632.764 us; speedup vs baseline: 2.4942x; 2.4942x over previous
//
#include <hip/hip_runtime.h>
#include <math.h>

#define Bsz  128
#define Lseq 256
#define Hdim 512
#define G4   2048
#define NWG  256
#define NT   512
#define RB   32      // batch rows per wg
#define LHP  516     // padded LDS row stride (floats)
#define OUTHALF (Bsz * Lseq * 2)   // 65536: planar split re | im

#define LH_ELEMS   (RB * LHP)                 // 16512
#define ZRED_ELEMS (2 * RB * 33)              // 2112: [lyz][row][col(33)], lyz0=z1 lyz1=z0
#define MLP_ELEMS  80
#define LDS_FLOATS (2 * LH_ELEMS + ZRED_ELEMS + MLP_ELEMS)  // 35216
#define LDS_BYTES  (LDS_FLOATS * 4)           // 140,864 B < 160 KiB -> 1 wg/CU

struct PArgs {
  const float *x, *Wx0, *Wh0, *b0, *Wx1, *Wh1, *b1;   // original layouts [K][4H]
  const float *Wr1, *br1, *Wr2, *br2, *Wi1, *bi1, *Wi2, *bi2;
  float *H0, *H1;                             // double-buffered [2][128][512]
  int   *cnt;                                 // 8 barrier counters (monotonic)
  float *out;                                 // f32 PLANAR: [re (B,L,2)][im (B,L,2)]
};

__device__ __forceinline__ float sigf(float z) {
  return 1.f / (1.f + expf(-z));
}

__global__ void __launch_bounds__(NT, 1) lstm_persist(PArgs A) {
  const int w    = blockIdx.x;
  const int tid  = threadIdx.x;
  // XCD-aware mapping: XCD x hosts cs in [8x,8x+8) -> contiguous cols per L2.
  const int cs   = (w & 7) * 8 + ((w >> 3) & 7);  // 0..63
  const int bg   = w >> 6;                         // 0..3
  const int r0   = bg * RB;
  const int c0   = cs * 8;
  // GEMM: wave q = col-quad (4 gate-cols), lane owns k in [lane*8, lane*8+8)
  const int q    = tid >> 6;            // 0..7
  const int lane = tid & 63;
  const int kb   = lane << 3;
  const int gq   = (q >> 1) * Hdim + c0 + (q & 1) * 4;
  // cell mapping (tid < 256): (row rr2, h-col hcc)
  const int rr2  = (tid >> 3) & 31;
  const int hcc  = tid & 7;
  // MLP mapping (tid < 256)
  const int wv   = (tid >> 6) & 3;

  extern __shared__ float lds[];
  float* lh0  = lds;                    // h0[p-1], rows r0..r0+31
  float* lh1  = lds + LH_ELEMS;         // h1[p-2]
  float* zred = lds + 2 * LH_ELEMS;     // [2][32][33]
  float* mlpb = zred + ZRED_ELEMS;      // [4 waves][20]

  // ---- load weights ONCE, register-stationary for all 258 phases (96 VGPRs) ----
  float4 wx1w[8], wh1w[8], wh0w[8];
#pragma unroll
  for (int j = 0; j < 8; ++j) {
    wx1w[j] = *(const float4*)&A.Wx1[(size_t)(kb + j) * G4 + gq];
    wh1w[j] = *(const float4*)&A.Wh1[(size_t)(kb + j) * G4 + gq];
    wh0w[j] = *(const float4*)&A.Wh0[(size_t)(kb + j) * G4 + gq];
  }

  // per-thread cell constants (tid < 256 only)
  float b0g[4], b1g[4], wx0a[4], wx0b[4];
  if (tid < 256) {
#pragma unroll
    for (int g = 0; g < 4; ++g) {
      int gc = g * Hdim + c0 + hcc;
      b0g[g]  = A.b0[gc];
      b1g[g]  = A.b1[gc];
      wx0a[g] = A.Wx0[gc];        // one-hot row 0 (x = -1)
      wx0b[g] = A.Wx0[G4 + gc];   // one-hot row 1 (x = +1)
    }
  }
  float c0s = 0.f, c1s = 0.f;

  const bool hi5 = (lane & 32) != 0;
  const bool hi4 = (lane & 16) != 0;
  const bool hi3 = (lane & 8)  != 0;
  const int  lyz  = hi5 ? 1 : 0;                      // 0 -> z1 block, 1 -> z0 block
  const int  cloc = (hi4 ? 2 : 0) + (hi3 ? 1 : 0);
  const int  zwidx = (lyz * RB) * 33 + q * 4 + cloc;  // + r*33 at write time

  for (int p = 0; p <= Lseq + 1; ++p) {
    // ---------- stage h0[p-1], h1[p-2]: sc1 u64 loads -> regs -> LDS ----------
    const unsigned long long* h0src8 =
      (const unsigned long long*)(A.H0 + (size_t)((p + 1) & 1) * (Bsz * Hdim) + (size_t)r0 * Hdim);
    const unsigned long long* h1src8 =
      (const unsigned long long*)(A.H1 + (size_t)(p & 1) * (Bsz * Hdim) + (size_t)r0 * Hdim);
    {
      unsigned long long v[16];
#pragma unroll
      for (int it = 0; it < 16; ++it) {
        int e = it * NT + tid;                  // 0..8191 (32 rows x 256 8B-chunks)
        v[it] = __hip_atomic_load(&h0src8[(e >> 8) * 256 + (e & 255)],
                                  __ATOMIC_RELAXED, __HIP_MEMORY_SCOPE_AGENT);
      }
#pragma unroll
      for (int it = 0; it < 16; ++it) {
        int e = it * NT + tid;
        *(unsigned long long*)&lh0[(e >> 8) * LHP + (e & 255) * 2] = v[it];
      }
#pragma unroll
      for (int it = 0; it < 16; ++it) {
        int e = it * NT + tid;
        v[it] = __hip_atomic_load(&h1src8[(e >> 8) * 256 + (e & 255)],
                                  __ATOMIC_RELAXED, __HIP_MEMORY_SCOPE_AGENT);
      }
#pragma unroll
      for (int it = 0; it < 16; ++it) {
        int e = it * NT + tid;
        *(unsigned long long*)&lh1[(e >> 8) * LHP + (e & 255) * 2] = v[it];
      }
    }
    __syncthreads();                          // sync A

    const bool doL1  = (p >= 1 && p <= Lseq);
    const bool doL0  = (p < Lseq);
    const bool doMLP = (p >= 2 && cs < 32 && tid < 256);

    float xv = 0.f;
    if (tid < 256 && p < Lseq) xv = A.x[(r0 + rr2) * Lseq + p];

    // ---------- GEMM: weights in registers; reduce-scatter butterfly ----------
#pragma unroll 2
    for (int r = 0; r < 32; ++r) {
      const float* lr0 = &lh0[r * LHP + kb];
      const float* lr1 = &lh1[r * LHP + kb];
      float4 ha = *(const float4*)lr0;
      float4 hb = *(const float4*)(lr0 + 4);
      float4 ga = *(const float4*)lr1;
      float4 gb = *(const float4*)(lr1 + 4);
      float h0v[8] = {ha.x, ha.y, ha.z, ha.w, hb.x, hb.y, hb.z, hb.w};
      float h1v[8] = {ga.x, ga.y, ga.z, ga.w, gb.x, gb.y, gb.z, gb.w};
      float hrv[8];
#pragma unroll
      for (int j = 0; j < 8; ++j) hrv[j] = fmaxf(h0v[j], 0.f);

      float4 az1 = {0.f, 0.f, 0.f, 0.f};
      float4 az0 = {0.f, 0.f, 0.f, 0.f};
#pragma unroll
      for (int j = 0; j < 8; ++j) {
        az1.x += hrv[j] * wx1w[j].x + h1v[j] * wh1w[j].x;
        az1.y += hrv[j] * wx1w[j].y + h1v[j] * wh1w[j].y;
        az1.z += hrv[j] * wx1w[j].z + h1v[j] * wh1w[j].z;
        az1.w += hrv[j] * wx1w[j].w + h1v[j] * wh1w[j].w;
        az0.x += h0v[j] * wh0w[j].x;
        az0.y += h0v[j] * wh0w[j].y;
        az0.z += h0v[j] * wh0w[j].z;
        az0.w += h0v[j] * wh0w[j].w;
      }

      // ---- reduce-scatter butterfly, ALL shuffles lane-uniform ----
      // stage 32: route layers (bit5=0 keeps z1, bit5=1 keeps z0)
      float s0x = hi5 ? az1.x : az0.x;       // send the half you don't own
      float s0y = hi5 ? az1.y : az0.y;
      float s0z = hi5 ? az1.z : az0.z;
      float s0w = hi5 ? az1.w : az0.w;
      float v0 = (hi5 ? az0.x : az1.x) + __shfl_xor(s0x, 32);
      float v1 = (hi5 ? az0.y : az1.y) + __shfl_xor(s0y, 32);
      float v2 = (hi5 ? az0.z : az1.z) + __shfl_xor(s0z, 32);
      float v3 = (hi5 ? az0.w : az1.w) + __shfl_xor(s0w, 32);
      // stage 16: cols {0,1} vs {2,3}
      float sendA = hi4 ? v0 : v2;
      float u0 = (hi4 ? v2 : v0) + __shfl_xor(sendA, 16);
      float sendB = hi4 ? v1 : v3;
      float u1 = (hi4 ? v3 : v1) + __shfl_xor(sendB, 16);
      // stage 8: even vs odd col
      float sendC = hi3 ? u0 : u1;
      float t = (hi3 ? u1 : u0) + __shfl_xor(sendC, 8);
      // finish: sum over lane bits 2..0
      t += __shfl_xor(t, 4);
      t += __shfl_xor(t, 2);
      t += __shfl_xor(t, 1);
      if ((lane & 7) == 0) zred[zwidx + r * 33] = t;
    }

    // ---------- MLP partials (waves 0-3; reads only lh1) ----------
    if (doMLP) {
      float pr[10], pi[10];
#pragma unroll
      for (int j = 0; j < 10; ++j) { pr[j] = 0.f; pi[j] = 0.f; }
#pragma unroll
      for (int i2 = 0; i2 < 2; ++i2) {
        int k = (wv << 7) + (i2 << 6) + lane;
        float hv = fmaxf(lh1[cs * LHP + k], 0.f);
#pragma unroll
        for (int j = 0; j < 10; ++j) {
          pr[j] += hv * A.Wr1[k * 10 + j];
          pi[j] += hv * A.Wi1[k * 10 + j];
        }
      }
#pragma unroll
      for (int j = 0; j < 10; ++j)
#pragma unroll
        for (int off = 32; off >= 1; off >>= 1) {
          pr[j] += __shfl_xor(pr[j], off);
          pi[j] += __shfl_xor(pi[j], off);
        }
      if ((tid & 63) == 0) {
#pragma unroll
        for (int j = 0; j < 10; ++j) { mlpb[wv * 20 + j] = pr[j]; mlpb[wv * 20 + 10 + j] = pi[j]; }
      }
    }
    __syncthreads();                          // sync B

    // ---------- cell updates (tid < 256) ----------
    if (tid < 256) {
      if (doL1) {
        float z[4];
#pragma unroll
        for (int g = 0; g < 4; ++g)
          z[g] = zred[(0 * RB + rr2) * 33 + g * 8 + hcc] + b1g[g];
        float ig = sigf(z[0]), fg = sigf(z[1]), gg = tanhf(z[2]), og = sigf(z[3]);
        c1s = fg * c1s + ig * gg;
        float hv = og * tanhf(c1s);
        float* H1w = A.H1 + (size_t)((p + 1) & 1) * (Bsz * Hdim);
        __hip_atomic_store(&H1w[(r0 + rr2) * Hdim + c0 + hcc], hv,
                           __ATOMIC_RELAXED, __HIP_MEMORY_SCOPE_AGENT);
      }
      if (doL0) {
        float z[4];
#pragma unroll
        for (int g = 0; g < 4; ++g)
          z[g] = zred[(1 * RB + rr2) * 33 + g * 8 + hcc]
               + b0g[g] + (xv > 0.f ? wx0b[g] : wx0a[g]);
        float ig = sigf(z[0]), fg = sigf(z[1]), gg = tanhf(z[2]), og = sigf(z[3]);
        c0s = fg * c0s + ig * gg;
        float hv = og * tanhf(c0s);
        float* H0w = A.H0 + (size_t)(p & 1) * (Bsz * Hdim);
        __hip_atomic_store(&H0w[(r0 + rr2) * Hdim + c0 + hcc], hv,
                           __ATOMIC_RELAXED, __HIP_MEMORY_SCOPE_AGENT);
      }
    }

    // ---------- MLP epilogue + output (f32 PLANAR re|im) ----------
    if (doMLP && tid == 0) {
      const int t2 = p - 2, b = r0 + cs;
      float rsum[2] = {A.br2[0], A.br2[1]};
      float isum[2] = {A.bi2[0], A.bi2[1]};
#pragma unroll
      for (int j = 0; j < 10; ++j) {
        float ar = mlpb[j] + mlpb[20 + j] + mlpb[40 + j] + mlpb[60 + j] + A.br1[j];
        ar = fmaxf(ar, 0.f);
        rsum[0] += ar * A.Wr2[j * 2];
        rsum[1] += ar * A.Wr2[j * 2 + 1];
        float ai = mlpb[10 + j] + mlpb[30 + j] + mlpb[50 + j] + mlpb[70 + j] + A.bi1[j];
        ai = fmaxf(ai, 0.f);
        isum[0] += ai * A.Wi2[j * 2];
        isum[1] += ai * A.Wi2[j * 2 + 1];
      }
#pragma unroll
      for (int m = 0; m < 2; ++m) {
        float im = 3.14159265358979323846f * (isum[m] / (1.f + fabsf(isum[m])));
        float sv, cv;
        sincosf(im, &sv, &cv);
        const int c = (b * Lseq + t2) * 2 + m;
        A.out[c]           = rsum[m] * cv;   // real
        A.out[OUTHALF + c] = rsum[m] * sv;   // imag
      }
    }

    // ---------- grid barrier: 8 monotonic counters, 8 pollers per wg ----------
    __syncthreads();
    if (tid == 0) {
      __hip_atomic_fetch_add(&A.cnt[w & 7], 1, __ATOMIC_RELEASE, __HIP_MEMORY_SCOPE_AGENT);
    }
    if (tid < 8) {
      const int target = (p + 1) * (NWG / 8);
      while (__hip_atomic_load(&A.cnt[tid], __ATOMIC_ACQUIRE, __HIP_MEMORY_SCOPE_AGENT) < target) {
        __builtin_amdgcn_s_sleep(2);
      }
    }
    __syncthreads();
  }
}

extern "C" void kernel_launch(void* const* d_in, const int* in_sizes, int n_in,
                              void* d_out, int out_size, void* d_ws, size_t ws_size,
                              hipStream_t stream) {
  const float* P[15];
  for (int i = 0; i < 15; ++i) P[i] = (const float*)d_in[i];
  if (in_sizes[0] != Bsz * Lseq) {
    static const int m_[15] = {14, 6, 0, 8, 7, 1, 9, 4, 12, 5, 13, 2, 10, 3, 11};
    for (int i = 0; i < 15; ++i) P[i] = (const float*)d_in[m_[i]];
  }

  PArgs a;
  a.x   = P[0];
  a.Wx0 = P[1];
  a.Wh0 = P[2];
  a.b0  = P[3];
  a.Wx1 = P[4];
  a.Wh1 = P[5];
  a.b1  = P[6];
  a.Wr1 = P[7];
  a.br1 = P[8];
  a.Wr2 = P[9];
  a.br2 = P[10];
  a.Wi1 = P[11];
  a.bi1 = P[12];
  a.Wi2 = P[13];
  a.bi2 = P[14];

  float* ws = (float*)d_ws;
  a.H0 = ws;
  a.H1 = ws + 2 * Bsz * Hdim;
  a.cnt = (int*)(ws + 4 * Bsz * Hdim);
  a.out = (float*)d_out;

  // zero H state (both parities) + counters every call (replay-safe)
  hipMemsetAsync(ws, 0, (size_t)(4 * Bsz * Hdim) * sizeof(float) + NWG * sizeof(int), stream);

  hipFuncSetAttribute((const void*)lstm_persist,
                      hipFuncAttributeMaxDynamicSharedMemorySize, LDS_BYTES);
  lstm_persist<<<dim3(NWG), dim3(NT), LDS_BYTES, stream>>>(a);
}